// Round 1
// 1569.811 us; speedup vs baseline: 1.8120x; 1.8120x over previous
//
#include <hip/hip_runtime.h>

// ---------------- problem dims ----------------
#define TT   512
#define DIN  1024
#define DH   2048
#define DOUT 1024

// ---------------- launch shape ----------------
#define NWG   256    // WGs 0..127: h1 chain (+epilogue); 128..255: h2 chain
#define HALF  128
#define NTHR  512    // 8 waves; each wave owns 2 h-rows of its chain
#define NSLOT (TT + 1)

typedef unsigned int u32;
typedef unsigned long long u64;

// One record per h element per step: {epoch (hi 32) | f32 bits (lo 32)}.
// A single u64 relaxed agent-scope store/load is architecturally atomic, so
// data and flag travel in ONE L3 round trip. Slot t is unique per step ->
// no ring reuse, no ABA, provably deadlock-free DAG. ~8.4 MB per chain.
//
// Epochs are offset by g_epoch_base (bumped +NSLOT per launch by a 1-thread
// pre-kernel), so records from previous runs can never alias the current
// run's targets -> the old 33.6 MB init memset is gone entirely.
__device__ u64 gR1[NSLOT * DH];   // h1 records
__device__ u64 gR2[NSLOT * DH];   // h2 records
__device__ u32 g_epoch_base;      // zero-init at module load; +=NSLOT per run

__device__ __forceinline__ float dot4(float4 a, float4 b) {
  return a.x * b.x + a.y * b.y + a.z * b.z + a.w * b.w;
}
__device__ __forceinline__ float wave_sum(float v) {
  #pragma unroll
  for (int off = 32; off > 0; off >>= 1) v += __shfl_down(v, off, 64);
  return v; // lane 0 holds the sum
}
__device__ __forceinline__ u64 ld_rec(const u64* p) {
  return __hip_atomic_load((u64*)p, __ATOMIC_RELAXED, __HIP_MEMORY_SCOPE_AGENT);
}
__device__ __forceinline__ void st_rec(u64* p, u64 v) {
  __hip_atomic_store(p, v, __ATOMIC_RELAXED, __HIP_MEMORY_SCOPE_AGENT);
}
__device__ __forceinline__ u64 pack(float h, u32 ep) {
  return ((u64)ep << 32) | (u64)__float_as_uint(h);
}
// Fast tanh, ~3 ulp, branch-free: only runs on lane 0 (2x per wave per step).
// Clamp keeps __expf in range; tanh(9) == 1.0f in fp32 anyway.
__device__ __forceinline__ float fast_tanh(float x) {
  float xc = fminf(fmaxf(x, -9.0f), 9.0f);
  float e  = __expf(2.0f * xc);
  return (e - 1.0f) * __frcp_rn(e + 1.0f);
}

// Poll this thread's 4 records of one slot until epoch matches, then deposit
// the floats into LDS.
// PENDING-ONLY RETRY: a record's u64 is final once its epoch matches (slot
// written exactly once), so it is latched in registers and NOT re-loaded.
// Retry traffic collapses from 16 KB/WG/retry to just the straggler lines —
// this is what un-congests the L3 and deflates the poll RT.
__device__ __forceinline__ void poll_stage(const u64* rec, u32 ep,
                                           float* lds, int tid) {
  u64 v0 = 0, v1 = 0, v2 = 0, v3 = 0;
  bool d0 = false, d1 = false, d2 = false, d3 = false;
  for (;;) {
    if (!d0) { v0 = ld_rec(rec + tid           ); d0 = ((u32)(v0 >> 32) == ep); }
    if (!d1) { v1 = ld_rec(rec + tid +     NTHR); d1 = ((u32)(v1 >> 32) == ep); }
    if (!d2) { v2 = ld_rec(rec + tid + 2 * NTHR); d2 = ((u32)(v2 >> 32) == ep); }
    if (!d3) { v3 = ld_rec(rec + tid + 3 * NTHR); d3 = ((u32)(v3 >> 32) == ep); }
    if (d0 & d1 & d2 & d3) break;
    __builtin_amdgcn_s_sleep(1);
  }
  lds[tid           ] = __uint_as_float((u32)v0);
  lds[tid +     NTHR] = __uint_as_float((u32)v1);
  lds[tid + 2 * NTHR] = __uint_as_float((u32)v2);
  lds[tid + 3 * NTHR] = __uint_as_float((u32)v3);
}

// Same for two slots at once (h2 chain: h1[t] and h2[t-1]). Pending-only
// retry means the already-arrived h1 block is not re-fetched while waiting
// on the h2 stragglers (previously 16 KB of dead reads per retry).
__device__ __forceinline__ void poll_stage2(const u64* recA, u32 epA,
                                            const u64* recB, u32 epB,
                                            float* ldsA, float* ldsB, int tid) {
  u64 a0 = 0, a1 = 0, a2 = 0, a3 = 0, b0 = 0, b1 = 0, b2 = 0, b3 = 0;
  bool da0 = false, da1 = false, da2 = false, da3 = false;
  bool db0 = false, db1 = false, db2 = false, db3 = false;
  for (;;) {
    if (!da0) { a0 = ld_rec(recA + tid           ); da0 = ((u32)(a0 >> 32) == epA); }
    if (!da1) { a1 = ld_rec(recA + tid +     NTHR); da1 = ((u32)(a1 >> 32) == epA); }
    if (!da2) { a2 = ld_rec(recA + tid + 2 * NTHR); da2 = ((u32)(a2 >> 32) == epA); }
    if (!da3) { a3 = ld_rec(recA + tid + 3 * NTHR); da3 = ((u32)(a3 >> 32) == epA); }
    if (!db0) { b0 = ld_rec(recB + tid           ); db0 = ((u32)(b0 >> 32) == epB); }
    if (!db1) { b1 = ld_rec(recB + tid +     NTHR); db1 = ((u32)(b1 >> 32) == epB); }
    if (!db2) { b2 = ld_rec(recB + tid + 2 * NTHR); db2 = ((u32)(b2 >> 32) == epB); }
    if (!db3) { b3 = ld_rec(recB + tid + 3 * NTHR); db3 = ((u32)(b3 >> 32) == epB); }
    if (da0 & da1 & da2 & da3 & db0 & db1 & db2 & db3) break;
    __builtin_amdgcn_s_sleep(1);
  }
  ldsA[tid           ] = __uint_as_float((u32)a0);
  ldsA[tid +     NTHR] = __uint_as_float((u32)a1);
  ldsA[tid + 2 * NTHR] = __uint_as_float((u32)a2);
  ldsA[tid + 3 * NTHR] = __uint_as_float((u32)a3);
  ldsB[tid           ] = __uint_as_float((u32)b0);
  ldsB[tid +     NTHR] = __uint_as_float((u32)b1);
  ldsB[tid + 2 * NTHR] = __uint_as_float((u32)b2);
  ldsB[tid + 3 * NTHR] = __uint_as_float((u32)b3);
}

// Advance the epoch base past all epochs any previous run could have stored.
// u32 wrap after ~8.4M replays is harmless (exact-match epochs, 1-run window).
__global__ void bump_kernel() {
  if (threadIdx.x == 0)
    __hip_atomic_fetch_add(&g_epoch_base, (u32)NSLOT,
                           __ATOMIC_RELAXED, __HIP_MEMORY_SCOPE_AGENT);
}

__global__ __launch_bounds__(NTHR, 2)
void rnn2_kernel(const float* __restrict__ X,
                 const float* __restrict__ Wa, const float* __restrict__ ba,
                 const float* __restrict__ Wb, const float* __restrict__ bb,
                 const float* __restrict__ Wc, const float* __restrict__ bc,
                 const float* __restrict__ Wd, const float* __restrict__ bd,
                 const float* __restrict__ Wo, const float* __restrict__ bo,
                 float* __restrict__ out)
{
  const int g   = blockIdx.x;
  const int tid = threadIdx.x;
  const int w   = tid >> 6;   // wave
  const int l   = tid & 63;   // lane

  // Uniform per-launch epoch base (bump_kernel ran earlier on this stream).
  const u32 eb = __hip_atomic_load(&g_epoch_base, __ATOMIC_RELAXED,
                                   __HIP_MEMORY_SCOPE_AGENT);

  // Double-buffered staging: stage(t) writes parity (t-1)&1 [h1] / t&1 [h2];
  // one barrier per step between stage and dot. Wave skew within a WG is
  // bounded by that barrier, so distance-2 buffer reuse is race-free.
  __shared__ float sA[2][DH];
  __shared__ float sB[2][DH];

  if (g < HALF) {
    // ================= h1 chain (+ output epilogue) =================
    const int r0 = g * 16 + 2 * w, r1 = r0 + 1;   // my two h1 rows
    float4 wA0[4], wA1[4], wB0[8], wB1[8], wO[8];
    {
      const float4* p0 = (const float4*)(Wa + (size_t)r0 * DIN);
      const float4* p1 = (const float4*)(Wa + (size_t)r1 * DIN);
      #pragma unroll
      for (int j = 0; j < 4; ++j) { wA0[j] = p0[l + 64 * j]; wA1[j] = p1[l + 64 * j]; }
    }
    {
      const float4* p0 = (const float4*)(Wb + (size_t)r0 * DH);
      const float4* p1 = (const float4*)(Wb + (size_t)r1 * DH);
      #pragma unroll
      for (int j = 0; j < 8; ++j) { wB0[j] = p0[l + 64 * j]; wB1[j] = p1[l + 64 * j]; }
    }
    const int orow = g * 8 + w;                   // my output row
    {
      const float4* p = (const float4*)(Wo + (size_t)orow * DH);
      #pragma unroll
      for (int j = 0; j < 8; ++j) wO[j] = p[l + 64 * j];
    }
    const float b1_0 = ba[r0] + bb[r0];
    const float b1_1 = ba[r1] + bb[r1];
    const float bo_r = bo[orow];

    for (int t = 1; t <= TT; ++t) {
      // A.x[t-1]: no cross-WG dependency — compute before the wait
      float a0 = 0.f, a1 = 0.f;
      {
        const float4* px = (const float4*)(X + (size_t)(t - 1) * DIN);
        #pragma unroll
        for (int j = 0; j < 4; ++j) {
          float4 x4 = px[l + 64 * j];
          a0 += dot4(wA0[j], x4);
          a1 += dot4(wA1[j], x4);
        }
      }
      if (t > 1) {
        float* buf = sA[(t - 1) & 1];
        poll_stage(gR1 + (size_t)(t - 1) * DH, eb + (u32)(t - 1), buf, tid);
        __syncthreads();
        const float4* ph = (const float4*)buf;
        #pragma unroll
        for (int j = 0; j < 8; ++j) {
          float4 h4 = ph[l + 64 * j];
          a0 += dot4(wB0[j], h4);
          a1 += dot4(wB1[j], h4);
        }
      }
      a0 = wave_sum(a0); a1 = wave_sum(a1);
      if (l == 0) {   // publish: two fire-and-forget atomic u64 records
        u64* dst = gR1 + (size_t)t * DH;
        st_rec(dst + r0, pack(fast_tanh(a0 + b1_0), eb + (u32)t));
        st_rec(dst + r1, pack(fast_tanh(a1 + b1_1), eb + (u32)t));
      }
    }

    // ---- epilogue: out = Wo . h2[TT] + bo (1 row per wave) ----
    // sA[0] has parity != the loop's last dot buffer (sA[1]) -> race-free.
    poll_stage(gR2 + (size_t)TT * DH, eb + (u32)TT, sA[0], tid);
    __syncthreads();
    {
      const float4* ph = (const float4*)sA[0];
      float acc = 0.f;
      #pragma unroll
      for (int j = 0; j < 8; ++j) acc += dot4(wO[j], ph[l + 64 * j]);
      acc = wave_sum(acc);
      if (l == 0) out[orow] = acc + bo_r;
    }
  } else {
    // ========================= h2 chain =========================
    const int gg = g - HALF;
    const int r0 = gg * 16 + 2 * w, r1 = r0 + 1;  // my two h2 rows
    float4 wC0[8], wC1[8], wD0[8], wD1[8];
    {
      const float4* p0 = (const float4*)(Wc + (size_t)r0 * DH);
      const float4* p1 = (const float4*)(Wc + (size_t)r1 * DH);
      #pragma unroll
      for (int j = 0; j < 8; ++j) { wC0[j] = p0[l + 64 * j]; wC1[j] = p1[l + 64 * j]; }
    }
    {
      const float4* p0 = (const float4*)(Wd + (size_t)r0 * DH);
      const float4* p1 = (const float4*)(Wd + (size_t)r1 * DH);
      #pragma unroll
      for (int j = 0; j < 8; ++j) { wD0[j] = p0[l + 64 * j]; wD1[j] = p1[l + 64 * j]; }
    }
    const float b2_0 = bc[r0] + bd[r0];
    const float b2_1 = bc[r1] + bd[r1];

    for (int t = 1; t <= TT; ++t) {
      float* bufA = sA[t & 1];
      float* bufB = sB[t & 1];
      if (t > 1)
        poll_stage2(gR1 + (size_t)t * DH, eb + (u32)t,
                    gR2 + (size_t)(t - 1) * DH, eb + (u32)(t - 1), bufA, bufB, tid);
      else
        poll_stage(gR1 + (size_t)t * DH, eb + (u32)t, bufA, tid);
      __syncthreads();

      float a0 = 0.f, a1 = 0.f;
      {
        const float4* ph = (const float4*)bufA;
        #pragma unroll
        for (int j = 0; j < 8; ++j) {
          float4 h4 = ph[l + 64 * j];
          a0 += dot4(wC0[j], h4);
          a1 += dot4(wC1[j], h4);
        }
      }
      if (t > 1) {
        const float4* ph = (const float4*)bufB;
        #pragma unroll
        for (int j = 0; j < 8; ++j) {
          float4 h4 = ph[l + 64 * j];
          a0 += dot4(wD0[j], h4);
          a1 += dot4(wD1[j], h4);
        }
      }
      a0 = wave_sum(a0); a1 = wave_sum(a1);
      if (l == 0) {
        u64* dst = gR2 + (size_t)t * DH;
        st_rec(dst + r0, pack(fast_tanh(a0 + b2_0), eb + (u32)t));
        st_rec(dst + r1, pack(fast_tanh(a1 + b2_1), eb + (u32)t));
      }
    }
  }
}

extern "C" void kernel_launch(void* const* d_in, const int* in_sizes, int n_in,
                              void* d_out, int out_size, void* d_ws, size_t ws_size,
                              hipStream_t stream)
{
  (void)in_sizes; (void)n_in; (void)out_size; (void)d_ws; (void)ws_size;

  const float* X  = (const float*)d_in[0];
  const float* Wa = (const float*)d_in[1];   // W_i2h1 [H][IN]
  const float* ba = (const float*)d_in[2];
  const float* Wb = (const float*)d_in[3];   // W_h2h1 [H][H]
  const float* bb = (const float*)d_in[4];
  // d_in[5], d_in[6]: W_h2o1 / b_h2o1 — dead code in the reference
  const float* Wc = (const float*)d_in[7];   // W_i2h2 [H][H]
  const float* bc = (const float*)d_in[8];
  const float* Wd = (const float*)d_in[9];   // W_h2h2 [H][H]
  const float* bd = (const float*)d_in[10];
  const float* Wo = (const float*)d_in[11];  // W_h2o2 [OUT][H]
  const float* bo = (const float*)d_in[12];
  float* out = (float*)d_out;

  bump_kernel<<<dim3(1), dim3(64), 0, stream>>>();

  void* args[] = { &X, &Wa, &ba, &Wb, &bb, &Wc, &bc, &Wd, &bd, &Wo, &bo, &out };
  (void)hipLaunchCooperativeKernel((void*)rnn2_kernel, dim3(NWG), dim3(NTHR),
                                   args, 0, stream);
}